// Round 7
// baseline (1473.748 us; speedup 1.0000x reference)
//
#include <hip/hip_runtime.h>
#include <hip/hip_bf16.h>
#include <stdint.h>

#define BB 16
#define NN 4096
#define NPOINT 1024
#define NSAMPLE 32

typedef unsigned int u32;
typedef unsigned long long u64;
typedef unsigned short u16;
typedef float f32x2 __attribute__((ext_vector_type(2)));
using frag_ab = __attribute__((ext_vector_type(8))) short;   // 8 bf16 (4 VGPRs)
using frag_cd = __attribute__((ext_vector_type(4))) float;   // 4 fp32

__device__ inline u16 f2bf(float x){ u32 u = __float_as_uint(x); u32 r = (u + 0x7fffu + ((u>>16)&1u)) >> 16; return (u16)r; }
__device__ inline float bf2f(u32 hbits){ return __uint_as_float(hbits<<16); }

// full-wave (64-lane) f32 max via DPP; result bits returned from lane 63.
__device__ inline int wave_max_bits(float v){
    int x = __float_as_int(v);
    int t;
    t = __builtin_amdgcn_update_dpp(0, x, 0x111, 0xf, 0xf, true);  // row_shr:1
    x = __float_as_int(fmaxf(__int_as_float(x), __int_as_float(t)));
    t = __builtin_amdgcn_update_dpp(0, x, 0x112, 0xf, 0xf, true);  // row_shr:2
    x = __float_as_int(fmaxf(__int_as_float(x), __int_as_float(t)));
    t = __builtin_amdgcn_update_dpp(0, x, 0x114, 0xf, 0xf, true);  // row_shr:4
    x = __float_as_int(fmaxf(__int_as_float(x), __int_as_float(t)));
    t = __builtin_amdgcn_update_dpp(0, x, 0x118, 0xf, 0xf, true);  // row_shr:8
    x = __float_as_int(fmaxf(__int_as_float(x), __int_as_float(t)));
    t = __builtin_amdgcn_update_dpp(0, x, 0x142, 0xf, 0xf, true);  // row_bcast:15
    x = __float_as_int(fmaxf(__int_as_float(x), __int_as_float(t)));
    t = __builtin_amdgcn_update_dpp(0, x, 0x143, 0xf, 0xf, true);  // row_bcast:31
    x = __float_as_int(fmaxf(__int_as_float(x), __int_as_float(t)));
    return __builtin_amdgcn_readlane(x, 63);
}

// ---------------- FPS: 4 waves, R3 in-loop tracking, BARRIER-FREE tag-poll exchange,
// ---------------- coords fused in slots + speculative per-lane coord prefetch ----------------
// Correctness of polling: all 4 waves live on ONE CU; LDS is physically shared, un-cached,
// and DS ops complete in issue order per wave. Parity double-buffer bounds wave skew to <2
// steps (a wave cannot pass a step until all 4 tags for that step are present), so a slot is
// never overwritten while a peer may still read it. Volatile on all slot accesses keeps order.
__global__ __launch_bounds__(256) void fps_kernel(const float* __restrict__ xyz, int* __restrict__ cents)
{
#pragma clang fp contract(off)
    __shared__ float lxyz[NN*3];
    __shared__ __align__(16) u32 sK[2][8];       // [par][w*2+0]=distbits, [w*2+1]=(4095-p)<<12 | tag
    __shared__ __align__(16) float sC[2][4][4];  // [par][w] = {x,y,z,pad}
    const int tid = threadIdx.x;
    const int b = blockIdx.x;
    const float* gx = xyz + (size_t)b*NN*3;
    for (int i = tid; i < NN*3; i += 256) lxyz[i] = gx[i];
    if (tid < 8){ sK[0][tid] = 0; sK[1][tid] = 0; }
    __syncthreads();
    // thread owns points p = tid*16 + j, j in [0,16)
    f32x2 px[8], py[8], pz[8], dist[8];
#pragma unroll
    for (int jj = 0; jj < 8; jj++){
        int p = tid*16 + jj*2;
        px[jj] = (f32x2){ lxyz[p*3+0], lxyz[(p+1)*3+0] };
        py[jj] = (f32x2){ lxyz[p*3+1], lxyz[(p+1)*3+1] };
        pz[jj] = (f32x2){ lxyz[p*3+2], lxyz[(p+1)*3+2] };
        dist[jj] = (f32x2){ 1e10f, 1e10f };
    }
    const int lane = tid & 63;
    const int wid = tid >> 6;
    int far = 0, par = 0;
    float cx = lxyz[0], cy = lxyz[1], cz = lxyz[2];
    for (int s = 0; s < NPOINT; s++){
        if (tid == 0) cents[b*NPOINT + s] = far;   // fire-and-forget global store
        f32x2 c2x = { cx, cx }, c2y = { cy, cy }, c2z = { cz, cz };
        float bv = -1.0f; int bj = 0;
#pragma unroll
        for (int jj = 0; jj < 8; jj++){
            f32x2 dx = px[jj] - c2x;
            f32x2 dy = py[jj] - c2y;
            f32x2 dz = pz[jj] - c2z;
            f32x2 d  = (dx*dx + dy*dy) + dz*dz;     // contract(off): exact _rn order
            f32x2 nd;
            nd.x = fminf(dist[jj].x, d.x);
            nd.y = fminf(dist[jj].y, d.y);
            dist[jj] = nd;
            if (nd.x > bv){ bv = nd.x; bj = jj*2; }       // ascending j => first-max kept
            if (nd.y > bv){ bv = nd.y; bj = jj*2+1; }
        }
        // speculative own-candidate coords (latency hides under DPP+ballot)
        const int p_loc = tid*16 + bj;
        float sx = lxyz[p_loc*3+0], sy = lxyz[p_loc*3+1], sz = lxyz[p_loc*3+2];
        int wmb = wave_max_bits(bv);
        float wmax = __int_as_float(wmb);
        u64 mask = __ballot(bv == wmax);
        int fl = __ffsll((long long)mask) - 1;             // lowest lane => lowest p
        int pw = __builtin_amdgcn_readlane(p_loc, fl);
        float qx = __int_as_float(__builtin_amdgcn_readlane(__float_as_int(sx), fl));
        float qy = __int_as_float(__builtin_amdgcn_readlane(__float_as_int(sy), fl));
        float qz = __int_as_float(__builtin_amdgcn_readlane(__float_as_int(sz), fl));
        const u32 tag = (u32)(s + 1);
        if (lane == 0){
            volatile float* vc = &sC[par][wid][0];
            vc[0] = qx; vc[1] = qy; vc[2] = qz;
            volatile u32* vk = &sK[par][wid*2];
            vk[0] = (u32)wmb;
            vk[1] = ((u32)(4095 - pw) << 12) | tag;        // tag last: publishes the slot
        }
        volatile u32* vk = &sK[par][0];
        u32 t0, t1, t2, t3;
        for (;;){
            t0 = vk[1]; t1 = vk[3]; t2 = vk[5]; t3 = vk[7];
            if ((((t0 ^ tag) | (t1 ^ tag) | (t2 ^ tag) | (t3 ^ tag)) & 0xFFFu) == 0) break;
        }
        u32 d0 = vk[0], d1 = vk[2], d2 = vk[4], d3 = vk[6];
        volatile float* vc = &sC[par][0][0];
        float x0 = vc[0],  y0 = vc[1],  z0 = vc[2];
        float x1 = vc[4],  y1 = vc[5],  z1 = vc[6];
        float x2v= vc[8],  y2 = vc[9],  z2 = vc[10];
        float x3 = vc[12], y3 = vc[13], z3 = vc[14];
        u64 k0 = ((u64)d0 << 32) | t0;
        u64 k1 = ((u64)d1 << 32) | t1;
        u64 k2 = ((u64)d2 << 32) | t2;
        u64 k3 = ((u64)d3 << 32) | t3;
        u64 bk = k0; float bx = x0, by = y0, bz = z0;
        if (k1 > bk){ bk = k1; bx = x1;  by = y1; bz = z1; }   // strict >: ties impossible (p unique)
        if (k2 > bk){ bk = k2; bx = x2v; by = y2; bz = z2; }
        if (k3 > bk){ bk = k3; bx = x3;  by = y3; bz = z3; }
        far = 4095 - (int)(((u32)bk >> 12) & 0xFFFu);
        cx = bx; cy = by; cz = bz;
        par ^= 1;
    }
}

// ---------------- gather new_xyz -> d_out[0:49152] and ws copy ----------------
__global__ __launch_bounds__(256) void gather_newxyz_kernel(const float* __restrict__ xyz, const int* __restrict__ cents,
                                                            float* __restrict__ out, float* __restrict__ nxyz)
{
    int i = blockIdx.x*256 + threadIdx.x;   // < 49152
    int b = i / 3072;
    int r = i - b*3072;
    int s = r / 3;
    int c = r - s*3;
    int idx = cents[b*NPOINT + s];
    float v = xyz[((size_t)b*NN + idx)*3 + c];
    out[i] = v;
    nxyz[i] = v;
}

// ---------------- points -> packed bf16 ----------------
__global__ __launch_bounds__(256) void pack_points_kernel(const float* __restrict__ points, u32* __restrict__ pbf)
{
    int i = blockIdx.x*256 + threadIdx.x;   // < 2097152
    float f0 = points[2*i], f1 = points[2*i+1];
    pbf[i] = (u32)f2bf(f0) | ((u32)f2bf(f1) << 16);
}

// ---------------- ball query: one wave per centroid, early exit ----------------
__global__ __launch_bounds__(256) void ballquery_kernel(const float* __restrict__ xyz, const float* __restrict__ nxyz,
                                                        const int* __restrict__ cents, int* __restrict__ gidx)
{
    const int lane = threadIdx.x & 63;
    const int w = (blockIdx.x << 2) + (threadIdx.x >> 6);
    const int b = w >> 10;
    const float RAD2 = (float)(0.9*0.9);
    const float* c3 = nxyz + (size_t)w*3;
    float cx = c3[0], cy = c3[1], cz = c3[2];
    float sc = __fadd_rn(__fadd_rn(__fmul_rn(cx,cx), __fmul_rn(cy,cy)), __fmul_rn(cz,cz));
    const float* gx = xyz + (size_t)b*NN*3;
    int* gout = gidx + (size_t)w*NSAMPLE;
    int found = 0; int first = -1;
    for (int base = 0; base < NN; base += 64){
        int i = base + lane;
        float pxv = gx[i*3+0], pyv = gx[i*3+1], pzv = gx[i*3+2];
        float sp = __fadd_rn(__fadd_rn(__fmul_rn(pxv,pxv), __fmul_rn(pyv,pyv)), __fmul_rn(pzv,pzv));
        float dot = __fadd_rn(__fadd_rn(__fmul_rn(cx,pxv), __fmul_rn(cy,pyv)), __fmul_rn(cz,pzv));
        float d2 = __fsub_rn(__fadd_rn(sc, sp), __fmul_rn(2.0f, dot));
        float dd = __fsqrt_rn(fmaxf(d2, 0.0f));
        bool in = !(dd > RAD2);
        u64 m = __ballot(in);
        int cnt = __popcll(m);
        if (in){
            int slot = found + __popcll(m & ((1ull<<lane) - 1ull));
            if (slot < NSAMPLE) gout[slot] = i;
        }
        if (found == 0 && cnt > 0) first = base + (__ffsll(m) - 1);
        found += cnt;
        if (found >= NSAMPLE) break;
    }
    if (found < NSAMPLE){
        if (found == 0) first = cents[w];
        for (int slot = found + lane; slot < NSAMPLE; slot += 64) gout[slot] = first;
    }
}

// ---------------- conv1 (MFMA): 67->64; points-part via MFMA on pre-packed bf16,
// ---------------- xyz-norm (3ch) + bias in fp32 epilogue; fused stats ----------------
__global__ __launch_bounds__(256) void conv1_kernel(const float* __restrict__ xyz, const u32* __restrict__ pbf,
                                                    const float* __restrict__ nxyz, const int* __restrict__ gidx,
                                                    const float* __restrict__ w, const float* __restrict__ bias,
                                                    u32* __restrict__ xout, float* __restrict__ stats)
{
    __shared__ float sxyz[512][3];
    const int tid = threadIdx.x;
    const int lane = tid & 63;
    const int wid = tid >> 6;
    const int quad = lane >> 4;
    const int col = lane & 15;
    const int blockbase = blockIdx.x*512;
    for (int r = tid; r < 512; r += 256){
        int m = blockbase + r;
        int b = m >> 15, s = (m >> 5) & 1023, g = gidx[m];
        const float* p3 = xyz + ((size_t)(b<<12) + g)*3;
        const float* c3 = nxyz + ((size_t)b*NPOINT + s)*3;
        sxyz[r][0] = p3[0]-c3[0]; sxyz[r][1] = p3[1]-c3[1]; sxyz[r][2] = p3[2]-c3[2];
    }
    frag_ab Bf[4][2];
#pragma unroll
    for (int nt = 0; nt < 4; nt++)
#pragma unroll
        for (int kh = 0; kh < 2; kh++){
            const float* wr = w + (nt*16 + col)*67 + 3 + kh*32 + quad*8;
#pragma unroll
            for (int j = 0; j < 8; j++) Bf[nt][kh][j] = (short)f2bf(wr[j]);
        }
    float wx[4], wy[4], wz[4], biasl[4];
#pragma unroll
    for (int nt = 0; nt < 4; nt++){
        const float* wb = w + (nt*16 + col)*67;
        wx[nt] = wb[0]; wy[nt] = wb[1]; wz[nt] = wb[2];
        biasl[nt] = bias[nt*16 + col];
    }
    __syncthreads();
    float ssum[4] = {0,0,0,0}, ssq[4] = {0,0,0,0};
    u16* xo = (u16*)xout;
    const int tile0 = blockIdx.x*32 + wid*8;
#pragma unroll 2
    for (int t = 0; t < 8; t++){
        const int tile = tile0 + t;
        const size_t m0 = (size_t)tile * 16;
        const int b = (int)(m0 >> 15);
        const int g = gidx[m0 + col];
        const u32* arow = pbf + ((size_t)(b<<12) + g)*32;
        uint4 u0 = *(const uint4*)(arow + quad*4);
        uint4 u1 = *(const uint4*)(arow + 16 + quad*4);
        frag_ab Af0, Af1;
        __builtin_memcpy(&Af0, &u0, 16);
        __builtin_memcpy(&Af1, &u1, 16);
        frag_cd acc[4];
#pragma unroll
        for (int nt = 0; nt < 4; nt++){
            acc[nt] = (frag_cd){0.f, 0.f, 0.f, 0.f};
            acc[nt] = __builtin_amdgcn_mfma_f32_16x16x32_bf16(Af0, Bf[nt][0], acc[nt], 0, 0, 0);
            acc[nt] = __builtin_amdgcn_mfma_f32_16x16x32_bf16(Af1, Bf[nt][1], acc[nt], 0, 0, 0);
        }
        const int rbase = (int)(m0 - blockbase) + quad*4;
#pragma unroll
        for (int r = 0; r < 4; r++){
            float xnx = sxyz[rbase+r][0], xny = sxyz[rbase+r][1], xnz = sxyz[rbase+r][2];
#pragma unroll
            for (int nt = 0; nt < 4; nt++){
                float v = acc[nt][r] + biasl[nt];
                v = fmaf(wx[nt], xnx, v);
                v = fmaf(wy[nt], xny, v);
                v = fmaf(wz[nt], xnz, v);
                xo[(m0 + quad*4 + r)*64 + nt*16 + col] = f2bf(v);
                ssum[nt] += v;
                ssq[nt] = fmaf(v, v, ssq[nt]);
            }
        }
    }
#pragma unroll
    for (int nt = 0; nt < 4; nt++){
        ssum[nt] += __shfl_xor(ssum[nt], 16); ssq[nt] += __shfl_xor(ssq[nt], 16);
        ssum[nt] += __shfl_xor(ssum[nt], 32); ssq[nt] += __shfl_xor(ssq[nt], 32);
    }
    if (quad == 0){
        float* st = stats + (blockIdx.x & 7)*256;
#pragma unroll
        for (int nt = 0; nt < 4; nt++){
            atomicAdd(&st[nt*16 + col], ssum[nt]);
            atomicAdd(&st[128 + nt*16 + col], ssq[nt]);
        }
    }
}

// ---- in-block BN finalize: stats (8 replicas) + g/beta -> saff[a:0..127 | b:128..255] ----
__device__ inline void block_finalize(const float* __restrict__ stats, const float* __restrict__ g,
                                      const float* __restrict__ beta, float* saff, int C, int tid)
{
    if (tid < C){
        float sm = 0.f, sq = 0.f;
#pragma unroll
        for (int r = 0; r < 8; r++){ sm += stats[r*256+tid]; sq += stats[r*256+128+tid]; }
        const float invM = 1.0f / 524288.0f;
        float mu  = sm * invM;
        float var = fmaxf(sq * invM - mu*mu, 0.0f);
        float inv = 1.0f / sqrtf(var + 1e-5f);
        float a = g[tid] * inv;
        saff[tid] = a;
        saff[128+tid] = beta[tid] - mu*a;
    }
}

// ---- unpack 8 packed-bf16, apply affine+relu, emit bf16 frag half ----
__device__ inline void unpack_affine_relu(uint4 u, const float* ak, const float* bk, short* dst){
    const u32* uu = (const u32*)&u;
#pragma unroll
    for (int q = 0; q < 4; q++){
        u32 v = uu[q];
        float x0 = bf2f(v & 0xffffu);
        float x1 = bf2f(v >> 16);
        float f0 = fmaxf(fmaf(ak[2*q],   x0, bk[2*q]),   0.f);
        float f1 = fmaxf(fmaf(ak[2*q+1], x1, bk[2*q+1]), 0.f);
        dst[2*q]   = (short)f2bf(f0);
        dst[2*q+1] = (short)f2bf(f1);
    }
}

// ---------------- conv2 (MFMA): 64->64, in-block BN0 finalize, BN+relu on load, fused stats ----------------
__global__ __launch_bounds__(256) void conv2_kernel(const u32* __restrict__ xin, const float* __restrict__ stats_in,
                                                    const float* __restrict__ gw, const float* __restrict__ beta,
                                                    const float* __restrict__ w, const float* __restrict__ bias,
                                                    u32* __restrict__ xout, float* __restrict__ stats)
{
    __shared__ float saff[256];
    const int tid = threadIdx.x;
    block_finalize(stats_in, gw, beta, saff, 64, tid);
    const int lane = tid & 63;
    const int wid = tid >> 6;
    const int quad = lane >> 4;
    const int col = lane & 15;
    frag_ab Bf[4][2];
#pragma unroll
    for (int nt = 0; nt < 4; nt++)
#pragma unroll
        for (int kh = 0; kh < 2; kh++){
            const float* wr = w + (nt*16 + col)*64 + kh*32 + quad*8;
#pragma unroll
            for (int j = 0; j < 8; j++) Bf[nt][kh][j] = (short)f2bf(wr[j]);
        }
    float biasl[4];
#pragma unroll
    for (int nt = 0; nt < 4; nt++) biasl[nt] = bias[nt*16 + col];
    __syncthreads();
    float ak[2][8], bk[2][8];
#pragma unroll
    for (int kh = 0; kh < 2; kh++)
#pragma unroll
        for (int j = 0; j < 8; j++){
            int k = kh*32 + quad*8 + j;
            ak[kh][j] = saff[k]; bk[kh][j] = saff[128+k];
        }
    float ssum[4] = {0,0,0,0}, ssq[4] = {0,0,0,0};
    u16* xo = (u16*)xout;
    const int tile0 = blockIdx.x*64 + wid*16;
    for (int t = 0; t < 16; t++){
        const size_t m0 = (size_t)(tile0 + t) * 16;
        const u32* arow = xin + (m0 + col)*32;
        uint4 u0 = *(const uint4*)(arow + quad*4);
        uint4 u1 = *(const uint4*)(arow + 16 + quad*4);
        frag_ab Af0, Af1;
        unpack_affine_relu(u0, ak[0], bk[0], (short*)&Af0);
        unpack_affine_relu(u1, ak[1], bk[1], (short*)&Af1);
        frag_cd acc[4];
#pragma unroll
        for (int nt = 0; nt < 4; nt++){
            acc[nt] = (frag_cd){biasl[nt], biasl[nt], biasl[nt], biasl[nt]};
            acc[nt] = __builtin_amdgcn_mfma_f32_16x16x32_bf16(Af0, Bf[nt][0], acc[nt], 0, 0, 0);
            acc[nt] = __builtin_amdgcn_mfma_f32_16x16x32_bf16(Af1, Bf[nt][1], acc[nt], 0, 0, 0);
        }
#pragma unroll
        for (int nt = 0; nt < 4; nt++){
#pragma unroll
            for (int r = 0; r < 4; r++){
                float v = acc[nt][r];
                xo[(m0 + quad*4 + r)*64 + nt*16 + col] = f2bf(v);
                ssum[nt] += v;
                ssq[nt] = fmaf(v, v, ssq[nt]);
            }
        }
    }
#pragma unroll
    for (int nt = 0; nt < 4; nt++){
        ssum[nt] += __shfl_xor(ssum[nt], 16); ssq[nt] += __shfl_xor(ssq[nt], 16);
        ssum[nt] += __shfl_xor(ssum[nt], 32); ssq[nt] += __shfl_xor(ssq[nt], 32);
    }
    if (quad == 0){
        float* st = stats + (blockIdx.x & 7)*256;
#pragma unroll
        for (int nt = 0; nt < 4; nt++){
            atomicAdd(&st[nt*16 + col], ssum[nt]);
            atomicAdd(&st[128 + nt*16 + col], ssq[nt]);
        }
    }
}

// ---------------- conv3 (MFMA): 64->128, in-block BN1 finalize, fused stats + group max/min ----------------
__global__ __launch_bounds__(256) void conv3_kernel(const u32* __restrict__ xin, const float* __restrict__ stats_in,
                                                    const float* __restrict__ gw, const float* __restrict__ beta,
                                                    const float* __restrict__ w, const float* __restrict__ bias,
                                                    float* __restrict__ gmax, float* __restrict__ gmin,
                                                    float* __restrict__ stats)
{
    __shared__ float saff[256];
    const int tid = threadIdx.x;
    block_finalize(stats_in, gw, beta, saff, 64, tid);
    const int lane = tid & 63;
    const int wid = tid >> 6;
    const int quad = lane >> 4;
    const int col = lane & 15;
    frag_ab Bf[8][2];
#pragma unroll
    for (int nt = 0; nt < 8; nt++)
#pragma unroll
        for (int kh = 0; kh < 2; kh++){
            const float* wr = w + (nt*16 + col)*64 + kh*32 + quad*8;
#pragma unroll
            for (int j = 0; j < 8; j++) Bf[nt][kh][j] = (short)f2bf(wr[j]);
        }
    float biasl[8];
#pragma unroll
    for (int nt = 0; nt < 8; nt++) biasl[nt] = bias[nt*16 + col];
    __syncthreads();
    float ak[2][8], bk[2][8];
#pragma unroll
    for (int kh = 0; kh < 2; kh++)
#pragma unroll
        for (int j = 0; j < 8; j++){
            int k = kh*32 + quad*8 + j;
            ak[kh][j] = saff[k]; bk[kh][j] = saff[128+k];
        }
    float ssum[8], ssq[8], mx[8], mn[8];
#pragma unroll
    for (int nt = 0; nt < 8; nt++){ ssum[nt] = 0.f; ssq[nt] = 0.f; }
    const int tile0 = blockIdx.x*32 + wid*8;
#pragma unroll 2
    for (int t = 0; t < 8; t++){
        const size_t m0 = (size_t)(tile0 + t) * 16;
        const u32* arow = xin + (m0 + col)*32;
        uint4 u0 = *(const uint4*)(arow + quad*4);
        uint4 u1 = *(const uint4*)(arow + 16 + quad*4);
        frag_ab Af0, Af1;
        unpack_affine_relu(u0, ak[0], bk[0], (short*)&Af0);
        unpack_affine_relu(u1, ak[1], bk[1], (short*)&Af1);
        frag_cd acc[8];
#pragma unroll
        for (int nt = 0; nt < 8; nt++){
            acc[nt] = (frag_cd){biasl[nt], biasl[nt], biasl[nt], biasl[nt]};
            acc[nt] = __builtin_amdgcn_mfma_f32_16x16x32_bf16(Af0, Bf[nt][0], acc[nt], 0, 0, 0);
            acc[nt] = __builtin_amdgcn_mfma_f32_16x16x32_bf16(Af1, Bf[nt][1], acc[nt], 0, 0, 0);
        }
#pragma unroll
        for (int nt = 0; nt < 8; nt++){
            float a0 = fmaxf(fmaxf(acc[nt][0], acc[nt][1]), fmaxf(acc[nt][2], acc[nt][3]));
            float n0 = fminf(fminf(acc[nt][0], acc[nt][1]), fminf(acc[nt][2], acc[nt][3]));
            if ((t & 1) == 0){ mx[nt] = a0; mn[nt] = n0; }
            else { mx[nt] = fmaxf(mx[nt], a0); mn[nt] = fminf(mn[nt], n0); }
#pragma unroll
            for (int r = 0; r < 4; r++){
                float v = acc[nt][r];
                ssum[nt] += v;
                ssq[nt] = fmaf(v, v, ssq[nt]);
            }
        }
        if (t & 1){
#pragma unroll
            for (int nt = 0; nt < 8; nt++){
                mx[nt] = fmaxf(mx[nt], __shfl_xor(mx[nt], 16));
                mn[nt] = fminf(mn[nt], __shfl_xor(mn[nt], 16));
                mx[nt] = fmaxf(mx[nt], __shfl_xor(mx[nt], 32));
                mn[nt] = fminf(mn[nt], __shfl_xor(mn[nt], 32));
            }
            if (quad == 0){
                const int g = (tile0 + t - 1) >> 1;
#pragma unroll
                for (int nt = 0; nt < 8; nt++){
                    gmax[(size_t)g*128 + nt*16 + col] = mx[nt];
                    gmin[(size_t)g*128 + nt*16 + col] = mn[nt];
                }
            }
        }
    }
#pragma unroll
    for (int nt = 0; nt < 8; nt++){
        ssum[nt] += __shfl_xor(ssum[nt], 16); ssq[nt] += __shfl_xor(ssq[nt], 16);
        ssum[nt] += __shfl_xor(ssum[nt], 32); ssq[nt] += __shfl_xor(ssq[nt], 32);
    }
    if (quad == 0){
        float* st = stats + (blockIdx.x & 7)*256;
#pragma unroll
        for (int nt = 0; nt < 8; nt++){
            atomicAdd(&st[nt*16 + col], ssum[nt]);
            atomicAdd(&st[128 + nt*16 + col], ssq[nt]);
        }
    }
}

// ---------------- pool: in-block BN2 finalize + relu from group max/min ----------------
__global__ __launch_bounds__(256) void pool_kernel(const float* __restrict__ gmax, const float* __restrict__ gmin,
                                                   const float* __restrict__ stats_in, const float* __restrict__ gw,
                                                   const float* __restrict__ beta, float* __restrict__ out)
{
    __shared__ float saff[256];
    const int tid = threadIdx.x;
    block_finalize(stats_in, gw, beta, saff, 128, tid);
    __syncthreads();
    const int base = blockIdx.x*2048 + tid;
#pragma unroll
    for (int k = 0; k < 8; k++){
        int idx = base + k*256;
        int o = idx & 127;
        float a = saff[o], bsh = saff[128+o];
        float v = (a >= 0.f) ? fmaf(a, gmax[idx], bsh) : fmaf(a, gmin[idx], bsh);
        out[(size_t)BB*NPOINT*3 + idx] = fmaxf(v, 0.f);
    }
}

extern "C" void kernel_launch(void* const* d_in, const int* in_sizes, int n_in,
                              void* d_out, int out_size, void* d_ws, size_t ws_size,
                              hipStream_t stream)
{
    const float* xyz    = (const float*)d_in[0];
    const float* points = (const float*)d_in[1];
    const float* w0  = (const float*)d_in[2];
    const float* b0  = (const float*)d_in[3];
    const float* g0  = (const float*)d_in[4];
    const float* be0 = (const float*)d_in[5];
    const float* w1  = (const float*)d_in[6];
    const float* b1  = (const float*)d_in[7];
    const float* g1  = (const float*)d_in[8];
    const float* be1 = (const float*)d_in[9];
    const float* w2  = (const float*)d_in[10];
    const float* b2  = (const float*)d_in[11];
    const float* g2  = (const float*)d_in[12];
    const float* be2 = (const float*)d_in[13];
    float* out = (float*)d_out;
    char* ws = (char*)d_ws;

    int*   cents = (int*)(ws + 0);                 //  64 KiB
    float* nxyz  = (float*)(ws + 65536);           // 192 KiB
    int*   gidx  = (int*)(ws + 262144);            //   2 MiB -> ends 2359296
    float* stats = (float*)(ws + 2359296);         //  24 KiB (3 layers x 8 replicas x 256 f)
    u32*   x1buf = (u32*)(ws + 2386944);           //  64 MiB (conv1 out bf16)
    u32*   x2buf = (u32*)(ws + 69495808);          //  64 MiB (conv2 out bf16)
    float* gmax  = (float*)(ws + 136604672);       // 8.4 MiB (conv3 out; aliases pbf - dead by then)
    float* gmin  = (float*)(ws + 144993280);       // 8.4 MiB
    u32*   pbf   = (u32*)(ws + 136604672);         // 8.4 MiB packed bf16 points (dead after conv1)

    hipMemsetAsync(stats, 0, 6144*sizeof(float), stream);
    fps_kernel<<<16, 256, 0, stream>>>(xyz, cents);
    gather_newxyz_kernel<<<192, 256, 0, stream>>>(xyz, cents, out, nxyz);
    pack_points_kernel<<<8192, 256, 0, stream>>>(points, pbf);
    ballquery_kernel<<<4096, 256, 0, stream>>>(xyz, nxyz, cents, gidx);
    conv1_kernel<<<1024, 256, 0, stream>>>(xyz, pbf, nxyz, gidx, w0, b0, x1buf, stats);
    conv2_kernel<<<512, 256, 0, stream>>>(x1buf, stats, g0, be0, w1, b1, x2buf, stats + 2048);
    conv3_kernel<<<1024, 256, 0, stream>>>(x2buf, stats + 2048, g1, be1, w2, b2, gmax, gmin, stats + 4096);
    pool_kernel<<<1024, 256, 0, stream>>>(gmax, gmin, stats + 4096, g2, be2, out);
}

// Round 8
// 760.039 us; speedup vs baseline: 1.9390x; 1.9390x over previous
//
#include <hip/hip_runtime.h>
#include <hip/hip_bf16.h>
#include <stdint.h>

#define BB 16
#define NN 4096
#define NPOINT 1024
#define NSAMPLE 32

typedef unsigned int u32;
typedef unsigned long long u64;
typedef unsigned short u16;
typedef float f32x2 __attribute__((ext_vector_type(2)));
using frag_ab = __attribute__((ext_vector_type(8))) short;   // 8 bf16 (4 VGPRs)
using frag_cd = __attribute__((ext_vector_type(4))) float;   // 4 fp32

__device__ inline u16 f2bf(float x){ u32 u = __float_as_uint(x); u32 r = (u + 0x7fffu + ((u>>16)&1u)) >> 16; return (u16)r; }
__device__ inline float bf2f(u32 hbits){ return __uint_as_float(hbits<<16); }
__device__ inline u64 umax64(u64 a, u64 b){ return a > b ? a : b; }

// full-wave (64-lane) f32 max via DPP; result bits returned from lane 63.
__device__ inline int wave_max_bits(float v){
    int x = __float_as_int(v);
    int t;
    t = __builtin_amdgcn_update_dpp(0, x, 0x111, 0xf, 0xf, true);  // row_shr:1
    x = __float_as_int(fmaxf(__int_as_float(x), __int_as_float(t)));
    t = __builtin_amdgcn_update_dpp(0, x, 0x112, 0xf, 0xf, true);  // row_shr:2
    x = __float_as_int(fmaxf(__int_as_float(x), __int_as_float(t)));
    t = __builtin_amdgcn_update_dpp(0, x, 0x114, 0xf, 0xf, true);  // row_shr:4
    x = __float_as_int(fmaxf(__int_as_float(x), __int_as_float(t)));
    t = __builtin_amdgcn_update_dpp(0, x, 0x118, 0xf, 0xf, true);  // row_shr:8
    x = __float_as_int(fmaxf(__int_as_float(x), __int_as_float(t)));
    t = __builtin_amdgcn_update_dpp(0, x, 0x142, 0xf, 0xf, true);  // row_bcast:15
    x = __float_as_int(fmaxf(__int_as_float(x), __int_as_float(t)));
    t = __builtin_amdgcn_update_dpp(0, x, 0x143, 0xf, 0xf, true);  // row_bcast:31
    x = __float_as_int(fmaxf(__int_as_float(x), __int_as_float(t)));
    return __builtin_amdgcn_readlane(x, 63);
}

// ---------------- FPS: R3-exact (best measured: 544 us). 4 waves, DPP value-max +
// ---------------- scalar index recovery, one barrier/step, global cents store ----------------
__global__ __launch_bounds__(256) void fps_kernel(const float* __restrict__ xyz, int* __restrict__ cents)
{
#pragma clang fp contract(off)
    __shared__ float lxyz[NN*3];
    __shared__ __align__(16) u64 s_red[2][4];
    const int tid = threadIdx.x;
    const int b = blockIdx.x;
    const float* gx = xyz + (size_t)b*NN*3;
    for (int i = tid; i < NN*3; i += 256) lxyz[i] = gx[i];
    __syncthreads();
    // chunked: thread owns points p = tid*16 + j, j in [0,16), stored as 8 float2 pairs
    f32x2 px[8], py[8], pz[8], dist[8];
#pragma unroll
    for (int jj = 0; jj < 8; jj++){
        int p = tid*16 + jj*2;
        px[jj] = (f32x2){ lxyz[p*3+0], lxyz[(p+1)*3+0] };
        py[jj] = (f32x2){ lxyz[p*3+1], lxyz[(p+1)*3+1] };
        pz[jj] = (f32x2){ lxyz[p*3+2], lxyz[(p+1)*3+2] };
        dist[jj] = (f32x2){ 1e10f, 1e10f };
    }
    const int lane = tid & 63;
    const int wid = tid >> 6;
    int far = 0, par = 0;
    for (int s = 0; s < NPOINT; s++){
        if (tid == 0) cents[b*NPOINT + s] = far;
        float cx = lxyz[far*3+0], cy = lxyz[far*3+1], cz = lxyz[far*3+2];
        f32x2 c2x = { cx, cx }, c2y = { cy, cy }, c2z = { cz, cz };
        float bv = -1.0f; int bj = 0;
#pragma unroll
        for (int jj = 0; jj < 8; jj++){
            f32x2 dx = px[jj] - c2x;
            f32x2 dy = py[jj] - c2y;
            f32x2 dz = pz[jj] - c2z;
            f32x2 d  = (dx*dx + dy*dy) + dz*dz;     // contract(off): exact _rn order
            f32x2 nd;
            nd.x = fminf(dist[jj].x, d.x);
            nd.y = fminf(dist[jj].y, d.y);
            dist[jj] = nd;
            if (nd.x > bv){ bv = nd.x; bj = jj*2; }       // ascending j => first-max kept
            if (nd.y > bv){ bv = nd.y; bj = jj*2+1; }
        }
        int wmb = wave_max_bits(bv);
        float wmax = __int_as_float(wmb);
        u64 mask = __ballot(bv == wmax);
        int fl = __ffsll((long long)mask) - 1;             // lowest lane => lowest p
        int fj = __builtin_amdgcn_readlane(bj, fl);
        int p = (wid << 10) + (fl << 4) + fj;
        if (lane == 0) s_red[par][wid] = ((u64)(u32)wmb << 32) | (u32)(4095 - p);
        __syncthreads();
        u64 m0 = umax64(s_red[par][0], s_red[par][1]);
        u64 m1 = umax64(s_red[par][2], s_red[par][3]);
        u64 m  = umax64(m0, m1);
        far = 4095 - (int)(m & 0xFFFu);
        par ^= 1;
    }
}

// ---------------- gather new_xyz -> d_out[0:49152] and ws copy ----------------
__global__ __launch_bounds__(256) void gather_newxyz_kernel(const float* __restrict__ xyz, const int* __restrict__ cents,
                                                            float* __restrict__ out, float* __restrict__ nxyz)
{
    int i = blockIdx.x*256 + threadIdx.x;   // < 49152
    int b = i / 3072;
    int r = i - b*3072;
    int s = r / 3;
    int c = r - s*3;
    int idx = cents[b*NPOINT + s];
    float v = xyz[((size_t)b*NN + idx)*3 + c];
    out[i] = v;
    nxyz[i] = v;
}

// ---------------- points -> packed bf16 ----------------
__global__ __launch_bounds__(256) void pack_points_kernel(const float* __restrict__ points, u32* __restrict__ pbf)
{
    int i = blockIdx.x*256 + threadIdx.x;   // < 2097152
    float f0 = points[2*i], f1 = points[2*i+1];
    pbf[i] = (u32)f2bf(f0) | ((u32)f2bf(f1) << 16);
}

// ---------------- ball query: one wave per centroid, early exit ----------------
__global__ __launch_bounds__(256) void ballquery_kernel(const float* __restrict__ xyz, const float* __restrict__ nxyz,
                                                        const int* __restrict__ cents, int* __restrict__ gidx)
{
    const int lane = threadIdx.x & 63;
    const int w = (blockIdx.x << 2) + (threadIdx.x >> 6);
    const int b = w >> 10;
    const float RAD2 = (float)(0.9*0.9);
    const float* c3 = nxyz + (size_t)w*3;
    float cx = c3[0], cy = c3[1], cz = c3[2];
    float sc = __fadd_rn(__fadd_rn(__fmul_rn(cx,cx), __fmul_rn(cy,cy)), __fmul_rn(cz,cz));
    const float* gx = xyz + (size_t)b*NN*3;
    int* gout = gidx + (size_t)w*NSAMPLE;
    int found = 0; int first = -1;
    for (int base = 0; base < NN; base += 64){
        int i = base + lane;
        float pxv = gx[i*3+0], pyv = gx[i*3+1], pzv = gx[i*3+2];
        float sp = __fadd_rn(__fadd_rn(__fmul_rn(pxv,pxv), __fmul_rn(pyv,pyv)), __fmul_rn(pzv,pzv));
        float dot = __fadd_rn(__fadd_rn(__fmul_rn(cx,pxv), __fmul_rn(cy,pyv)), __fmul_rn(cz,pzv));
        float d2 = __fsub_rn(__fadd_rn(sc, sp), __fmul_rn(2.0f, dot));
        float dd = __fsqrt_rn(fmaxf(d2, 0.0f));
        bool in = !(dd > RAD2);
        u64 m = __ballot(in);
        int cnt = __popcll(m);
        if (in){
            int slot = found + __popcll(m & ((1ull<<lane) - 1ull));
            if (slot < NSAMPLE) gout[slot] = i;
        }
        if (found == 0 && cnt > 0) first = base + (__ffsll(m) - 1);
        found += cnt;
        if (found >= NSAMPLE) break;
    }
    if (found < NSAMPLE){
        if (found == 0) first = cents[w];
        for (int slot = found + lane; slot < NSAMPLE; slot += 64) gout[slot] = first;
    }
}

// ---------------- conv1 (MFMA): 67->64; points-part via MFMA on pre-packed bf16,
// ---------------- xyz-norm (3ch) + bias in fp32 epilogue; fused stats ----------------
__global__ __launch_bounds__(256) void conv1_kernel(const float* __restrict__ xyz, const u32* __restrict__ pbf,
                                                    const float* __restrict__ nxyz, const int* __restrict__ gidx,
                                                    const float* __restrict__ w, const float* __restrict__ bias,
                                                    u32* __restrict__ xout, float* __restrict__ stats)
{
    __shared__ float sxyz[512][3];
    const int tid = threadIdx.x;
    const int lane = tid & 63;
    const int wid = tid >> 6;
    const int quad = lane >> 4;
    const int col = lane & 15;
    const int blockbase = blockIdx.x*512;
    for (int r = tid; r < 512; r += 256){
        int m = blockbase + r;
        int b = m >> 15, s = (m >> 5) & 1023, g = gidx[m];
        const float* p3 = xyz + ((size_t)(b<<12) + g)*3;
        const float* c3 = nxyz + ((size_t)b*NPOINT + s)*3;
        sxyz[r][0] = p3[0]-c3[0]; sxyz[r][1] = p3[1]-c3[1]; sxyz[r][2] = p3[2]-c3[2];
    }
    frag_ab Bf[4][2];
#pragma unroll
    for (int nt = 0; nt < 4; nt++)
#pragma unroll
        for (int kh = 0; kh < 2; kh++){
            const float* wr = w + (nt*16 + col)*67 + 3 + kh*32 + quad*8;
#pragma unroll
            for (int j = 0; j < 8; j++) Bf[nt][kh][j] = (short)f2bf(wr[j]);
        }
    float wx[4], wy[4], wz[4], biasl[4];
#pragma unroll
    for (int nt = 0; nt < 4; nt++){
        const float* wb = w + (nt*16 + col)*67;
        wx[nt] = wb[0]; wy[nt] = wb[1]; wz[nt] = wb[2];
        biasl[nt] = bias[nt*16 + col];
    }
    __syncthreads();
    float ssum[4] = {0,0,0,0}, ssq[4] = {0,0,0,0};
    u16* xo = (u16*)xout;
    const int tile0 = blockIdx.x*32 + wid*8;
#pragma unroll 2
    for (int t = 0; t < 8; t++){
        const int tile = tile0 + t;
        const size_t m0 = (size_t)tile * 16;
        const int b = (int)(m0 >> 15);
        const int g = gidx[m0 + col];
        const u32* arow = pbf + ((size_t)(b<<12) + g)*32;
        uint4 u0 = *(const uint4*)(arow + quad*4);
        uint4 u1 = *(const uint4*)(arow + 16 + quad*4);
        frag_ab Af0, Af1;
        __builtin_memcpy(&Af0, &u0, 16);
        __builtin_memcpy(&Af1, &u1, 16);
        frag_cd acc[4];
#pragma unroll
        for (int nt = 0; nt < 4; nt++){
            acc[nt] = (frag_cd){0.f, 0.f, 0.f, 0.f};
            acc[nt] = __builtin_amdgcn_mfma_f32_16x16x32_bf16(Af0, Bf[nt][0], acc[nt], 0, 0, 0);
            acc[nt] = __builtin_amdgcn_mfma_f32_16x16x32_bf16(Af1, Bf[nt][1], acc[nt], 0, 0, 0);
        }
        const int rbase = (int)(m0 - blockbase) + quad*4;
#pragma unroll
        for (int r = 0; r < 4; r++){
            float xnx = sxyz[rbase+r][0], xny = sxyz[rbase+r][1], xnz = sxyz[rbase+r][2];
#pragma unroll
            for (int nt = 0; nt < 4; nt++){
                float v = acc[nt][r] + biasl[nt];
                v = fmaf(wx[nt], xnx, v);
                v = fmaf(wy[nt], xny, v);
                v = fmaf(wz[nt], xnz, v);
                xo[(m0 + quad*4 + r)*64 + nt*16 + col] = f2bf(v);
                ssum[nt] += v;
                ssq[nt] = fmaf(v, v, ssq[nt]);
            }
        }
    }
#pragma unroll
    for (int nt = 0; nt < 4; nt++){
        ssum[nt] += __shfl_xor(ssum[nt], 16); ssq[nt] += __shfl_xor(ssq[nt], 16);
        ssum[nt] += __shfl_xor(ssum[nt], 32); ssq[nt] += __shfl_xor(ssq[nt], 32);
    }
    if (quad == 0){
        float* st = stats + (blockIdx.x & 7)*256;
#pragma unroll
        for (int nt = 0; nt < 4; nt++){
            atomicAdd(&st[nt*16 + col], ssum[nt]);
            atomicAdd(&st[128 + nt*16 + col], ssq[nt]);
        }
    }
}

// ---- in-block BN finalize: stats (8 replicas) + g/beta -> saff[a:0..127 | b:128..255] ----
__device__ inline void block_finalize(const float* __restrict__ stats, const float* __restrict__ g,
                                      const float* __restrict__ beta, float* saff, int C, int tid)
{
    if (tid < C){
        float sm = 0.f, sq = 0.f;
#pragma unroll
        for (int r = 0; r < 8; r++){ sm += stats[r*256+tid]; sq += stats[r*256+128+tid]; }
        const float invM = 1.0f / 524288.0f;
        float mu  = sm * invM;
        float var = fmaxf(sq * invM - mu*mu, 0.0f);
        float inv = 1.0f / sqrtf(var + 1e-5f);
        float a = g[tid] * inv;
        saff[tid] = a;
        saff[128+tid] = beta[tid] - mu*a;
    }
}

// ---- unpack 8 packed-bf16, apply affine+relu, emit bf16 frag half ----
__device__ inline void unpack_affine_relu(uint4 u, const float* ak, const float* bk, short* dst){
    const u32* uu = (const u32*)&u;
#pragma unroll
    for (int q = 0; q < 4; q++){
        u32 v = uu[q];
        float x0 = bf2f(v & 0xffffu);
        float x1 = bf2f(v >> 16);
        float f0 = fmaxf(fmaf(ak[2*q],   x0, bk[2*q]),   0.f);
        float f1 = fmaxf(fmaf(ak[2*q+1], x1, bk[2*q+1]), 0.f);
        dst[2*q]   = (short)f2bf(f0);
        dst[2*q+1] = (short)f2bf(f1);
    }
}

// ---------------- conv2 (MFMA): 64->64, in-block BN0 finalize, BN+relu on load, fused stats ----------------
__global__ __launch_bounds__(256) void conv2_kernel(const u32* __restrict__ xin, const float* __restrict__ stats_in,
                                                    const float* __restrict__ gw, const float* __restrict__ beta,
                                                    const float* __restrict__ w, const float* __restrict__ bias,
                                                    u32* __restrict__ xout, float* __restrict__ stats)
{
    __shared__ float saff[256];
    const int tid = threadIdx.x;
    block_finalize(stats_in, gw, beta, saff, 64, tid);
    const int lane = tid & 63;
    const int wid = tid >> 6;
    const int quad = lane >> 4;
    const int col = lane & 15;
    frag_ab Bf[4][2];
#pragma unroll
    for (int nt = 0; nt < 4; nt++)
#pragma unroll
        for (int kh = 0; kh < 2; kh++){
            const float* wr = w + (nt*16 + col)*64 + kh*32 + quad*8;
#pragma unroll
            for (int j = 0; j < 8; j++) Bf[nt][kh][j] = (short)f2bf(wr[j]);
        }
    float biasl[4];
#pragma unroll
    for (int nt = 0; nt < 4; nt++) biasl[nt] = bias[nt*16 + col];
    __syncthreads();
    float ak[2][8], bk[2][8];
#pragma unroll
    for (int kh = 0; kh < 2; kh++)
#pragma unroll
        for (int j = 0; j < 8; j++){
            int k = kh*32 + quad*8 + j;
            ak[kh][j] = saff[k]; bk[kh][j] = saff[128+k];
        }
    float ssum[4] = {0,0,0,0}, ssq[4] = {0,0,0,0};
    u16* xo = (u16*)xout;
    const int tile0 = blockIdx.x*64 + wid*16;
    for (int t = 0; t < 16; t++){
        const size_t m0 = (size_t)(tile0 + t) * 16;
        const u32* arow = xin + (m0 + col)*32;
        uint4 u0 = *(const uint4*)(arow + quad*4);
        uint4 u1 = *(const uint4*)(arow + 16 + quad*4);
        frag_ab Af0, Af1;
        unpack_affine_relu(u0, ak[0], bk[0], (short*)&Af0);
        unpack_affine_relu(u1, ak[1], bk[1], (short*)&Af1);
        frag_cd acc[4];
#pragma unroll
        for (int nt = 0; nt < 4; nt++){
            acc[nt] = (frag_cd){biasl[nt], biasl[nt], biasl[nt], biasl[nt]};
            acc[nt] = __builtin_amdgcn_mfma_f32_16x16x32_bf16(Af0, Bf[nt][0], acc[nt], 0, 0, 0);
            acc[nt] = __builtin_amdgcn_mfma_f32_16x16x32_bf16(Af1, Bf[nt][1], acc[nt], 0, 0, 0);
        }
#pragma unroll
        for (int nt = 0; nt < 4; nt++){
#pragma unroll
            for (int r = 0; r < 4; r++){
                float v = acc[nt][r];
                xo[(m0 + quad*4 + r)*64 + nt*16 + col] = f2bf(v);
                ssum[nt] += v;
                ssq[nt] = fmaf(v, v, ssq[nt]);
            }
        }
    }
#pragma unroll
    for (int nt = 0; nt < 4; nt++){
        ssum[nt] += __shfl_xor(ssum[nt], 16); ssq[nt] += __shfl_xor(ssq[nt], 16);
        ssum[nt] += __shfl_xor(ssum[nt], 32); ssq[nt] += __shfl_xor(ssq[nt], 32);
    }
    if (quad == 0){
        float* st = stats + (blockIdx.x & 7)*256;
#pragma unroll
        for (int nt = 0; nt < 4; nt++){
            atomicAdd(&st[nt*16 + col], ssum[nt]);
            atomicAdd(&st[128 + nt*16 + col], ssq[nt]);
        }
    }
}

// ---------------- conv3 (MFMA): 64->128, in-block BN1 finalize, fused stats + group max/min ----------------
__global__ __launch_bounds__(256) void conv3_kernel(const u32* __restrict__ xin, const float* __restrict__ stats_in,
                                                    const float* __restrict__ gw, const float* __restrict__ beta,
                                                    const float* __restrict__ w, const float* __restrict__ bias,
                                                    float* __restrict__ gmax, float* __restrict__ gmin,
                                                    float* __restrict__ stats)
{
    __shared__ float saff[256];
    const int tid = threadIdx.x;
    block_finalize(stats_in, gw, beta, saff, 64, tid);
    const int lane = tid & 63;
    const int wid = tid >> 6;
    const int quad = lane >> 4;
    const int col = lane & 15;
    frag_ab Bf[8][2];
#pragma unroll
    for (int nt = 0; nt < 8; nt++)
#pragma unroll
        for (int kh = 0; kh < 2; kh++){
            const float* wr = w + (nt*16 + col)*64 + kh*32 + quad*8;
#pragma unroll
            for (int j = 0; j < 8; j++) Bf[nt][kh][j] = (short)f2bf(wr[j]);
        }
    float biasl[8];
#pragma unroll
    for (int nt = 0; nt < 8; nt++) biasl[nt] = bias[nt*16 + col];
    __syncthreads();
    float ak[2][8], bk[2][8];
#pragma unroll
    for (int kh = 0; kh < 2; kh++)
#pragma unroll
        for (int j = 0; j < 8; j++){
            int k = kh*32 + quad*8 + j;
            ak[kh][j] = saff[k]; bk[kh][j] = saff[128+k];
        }
    float ssum[8], ssq[8], mx[8], mn[8];
#pragma unroll
    for (int nt = 0; nt < 8; nt++){ ssum[nt] = 0.f; ssq[nt] = 0.f; }
    const int tile0 = blockIdx.x*32 + wid*8;
#pragma unroll 2
    for (int t = 0; t < 8; t++){
        const size_t m0 = (size_t)(tile0 + t) * 16;
        const u32* arow = xin + (m0 + col)*32;
        uint4 u0 = *(const uint4*)(arow + quad*4);
        uint4 u1 = *(const uint4*)(arow + 16 + quad*4);
        frag_ab Af0, Af1;
        unpack_affine_relu(u0, ak[0], bk[0], (short*)&Af0);
        unpack_affine_relu(u1, ak[1], bk[1], (short*)&Af1);
        frag_cd acc[8];
#pragma unroll
        for (int nt = 0; nt < 8; nt++){
            acc[nt] = (frag_cd){biasl[nt], biasl[nt], biasl[nt], biasl[nt]};
            acc[nt] = __builtin_amdgcn_mfma_f32_16x16x32_bf16(Af0, Bf[nt][0], acc[nt], 0, 0, 0);
            acc[nt] = __builtin_amdgcn_mfma_f32_16x16x32_bf16(Af1, Bf[nt][1], acc[nt], 0, 0, 0);
        }
#pragma unroll
        for (int nt = 0; nt < 8; nt++){
            float a0 = fmaxf(fmaxf(acc[nt][0], acc[nt][1]), fmaxf(acc[nt][2], acc[nt][3]));
            float n0 = fminf(fminf(acc[nt][0], acc[nt][1]), fminf(acc[nt][2], acc[nt][3]));
            if ((t & 1) == 0){ mx[nt] = a0; mn[nt] = n0; }
            else { mx[nt] = fmaxf(mx[nt], a0); mn[nt] = fminf(mn[nt], n0); }
#pragma unroll
            for (int r = 0; r < 4; r++){
                float v = acc[nt][r];
                ssum[nt] += v;
                ssq[nt] = fmaf(v, v, ssq[nt]);
            }
        }
        if (t & 1){
#pragma unroll
            for (int nt = 0; nt < 8; nt++){
                mx[nt] = fmaxf(mx[nt], __shfl_xor(mx[nt], 16));
                mn[nt] = fminf(mn[nt], __shfl_xor(mn[nt], 16));
                mx[nt] = fmaxf(mx[nt], __shfl_xor(mx[nt], 32));
                mn[nt] = fminf(mn[nt], __shfl_xor(mn[nt], 32));
            }
            if (quad == 0){
                const int g = (tile0 + t - 1) >> 1;
#pragma unroll
                for (int nt = 0; nt < 8; nt++){
                    gmax[(size_t)g*128 + nt*16 + col] = mx[nt];
                    gmin[(size_t)g*128 + nt*16 + col] = mn[nt];
                }
            }
        }
    }
#pragma unroll
    for (int nt = 0; nt < 8; nt++){
        ssum[nt] += __shfl_xor(ssum[nt], 16); ssq[nt] += __shfl_xor(ssq[nt], 16);
        ssum[nt] += __shfl_xor(ssum[nt], 32); ssq[nt] += __shfl_xor(ssq[nt], 32);
    }
    if (quad == 0){
        float* st = stats + (blockIdx.x & 7)*256;
#pragma unroll
        for (int nt = 0; nt < 8; nt++){
            atomicAdd(&st[nt*16 + col], ssum[nt]);
            atomicAdd(&st[128 + nt*16 + col], ssq[nt]);
        }
    }
}

// ---------------- pool: in-block BN2 finalize + relu from group max/min ----------------
__global__ __launch_bounds__(256) void pool_kernel(const float* __restrict__ gmax, const float* __restrict__ gmin,
                                                   const float* __restrict__ stats_in, const float* __restrict__ gw,
                                                   const float* __restrict__ beta, float* __restrict__ out)
{
    __shared__ float saff[256];
    const int tid = threadIdx.x;
    block_finalize(stats_in, gw, beta, saff, 128, tid);
    __syncthreads();
    const int base = blockIdx.x*2048 + tid;
#pragma unroll
    for (int k = 0; k < 8; k++){
        int idx = base + k*256;
        int o = idx & 127;
        float a = saff[o], bsh = saff[128+o];
        float v = (a >= 0.f) ? fmaf(a, gmax[idx], bsh) : fmaf(a, gmin[idx], bsh);
        out[(size_t)BB*NPOINT*3 + idx] = fmaxf(v, 0.f);
    }
}

extern "C" void kernel_launch(void* const* d_in, const int* in_sizes, int n_in,
                              void* d_out, int out_size, void* d_ws, size_t ws_size,
                              hipStream_t stream)
{
    const float* xyz    = (const float*)d_in[0];
    const float* points = (const float*)d_in[1];
    const float* w0  = (const float*)d_in[2];
    const float* b0  = (const float*)d_in[3];
    const float* g0  = (const float*)d_in[4];
    const float* be0 = (const float*)d_in[5];
    const float* w1  = (const float*)d_in[6];
    const float* b1  = (const float*)d_in[7];
    const float* g1  = (const float*)d_in[8];
    const float* be1 = (const float*)d_in[9];
    const float* w2  = (const float*)d_in[10];
    const float* b2  = (const float*)d_in[11];
    const float* g2  = (const float*)d_in[12];
    const float* be2 = (const float*)d_in[13];
    float* out = (float*)d_out;
    char* ws = (char*)d_ws;

    int*   cents = (int*)(ws + 0);                 //  64 KiB
    float* nxyz  = (float*)(ws + 65536);           // 192 KiB
    int*   gidx  = (int*)(ws + 262144);            //   2 MiB -> ends 2359296
    float* stats = (float*)(ws + 2359296);         //  24 KiB (3 layers x 8 replicas x 256 f)
    u32*   x1buf = (u32*)(ws + 2386944);           //  64 MiB (conv1 out bf16)
    u32*   x2buf = (u32*)(ws + 69495808);          //  64 MiB (conv2 out bf16)
    float* gmax  = (float*)(ws + 136604672);       // 8.4 MiB (conv3 out; aliases pbf - dead by then)
    float* gmin  = (float*)(ws + 144993280);       // 8.4 MiB
    u32*   pbf   = (u32*)(ws + 136604672);         // 8.4 MiB packed bf16 points (dead after conv1)

    hipMemsetAsync(stats, 0, 6144*sizeof(float), stream);
    fps_kernel<<<16, 256, 0, stream>>>(xyz, cents);
    gather_newxyz_kernel<<<192, 256, 0, stream>>>(xyz, cents, out, nxyz);
    pack_points_kernel<<<8192, 256, 0, stream>>>(points, pbf);
    ballquery_kernel<<<4096, 256, 0, stream>>>(xyz, nxyz, cents, gidx);
    conv1_kernel<<<1024, 256, 0, stream>>>(xyz, pbf, nxyz, gidx, w0, b0, x1buf, stats);
    conv2_kernel<<<512, 256, 0, stream>>>(x1buf, stats, g0, be0, w1, b1, x2buf, stats + 2048);
    conv3_kernel<<<1024, 256, 0, stream>>>(x2buf, stats + 2048, g1, be1, w2, b2, gmax, gmin, stats + 4096);
    pool_kernel<<<1024, 256, 0, stream>>>(gmax, gmin, stats + 4096, g2, be2, out);
}